// Round 12
// baseline (207.987 us; speedup 1.0000x reference)
//
#include <hip/hip_runtime.h>

#define NN      4096
#define FEAT    512
#define NHID    64
#define NHEADS  8
#define NCLS    16
#define MAXDEG  128
#define ALPHA   0.2f

typedef __bf16 bf16_t;
typedef __bf16 bf16x8_t __attribute__((ext_vector_type(8)));
typedef float  f32x4_t  __attribute__((ext_vector_type(4)));
typedef unsigned short us8_t __attribute__((ext_vector_type(8)));

__device__ inline unsigned short f2bf(float f) {
    unsigned int u = __float_as_uint(f);
    u += 0x7fffu + ((u >> 16) & 1u);          // round-to-nearest-even
    return (unsigned short)(u >> 16);
}
__device__ inline float bfu2f(unsigned short b) {
    return __uint_as_float(((unsigned int)b) << 16);
}

// ---------------------------------------------------------------------------
// Fused front-end (one launch, 8196 blocks of 256):
//   blocks [0,4096):     adj row b -> 16-bit nonzero masks (PURE stream:
//                        4 float4 loads + one 2B store per thread; no LDS,
//                        no barrier, no dependent chain — m13 copy structure).
//   blocks [4096,6144):  R = adj_ad@rel, Abf = bf16(x+R)  (2 rows/block)
//   blocks [6144,8196):  weight permutes + f1o/f2o zero-init
// bitmap[r*256 + c16] bit s covers column 16*c16 + s.
__global__ __launch_bounds__(256) void prep_kernel(
    const float* __restrict__ adj, unsigned short* __restrict__ bitmap,
    const float* __restrict__ adj_ad, const float* __restrict__ rel,
    const float* __restrict__ x, float* __restrict__ R, bf16_t* __restrict__ Abf,
    const float* __restrict__ Wh, const float* __restrict__ Wo,
    unsigned short* __restrict__ WcT, unsigned short* __restrict__ WoT,
    float* __restrict__ f1o, float* __restrict__ f2o) {
    int b = blockIdx.x;
    int t = threadIdx.x;
    __shared__ float sa[2][64];
    if (b < NN) {
        // ---- bitmap build: thread t covers columns [16t, 16t+16) of row b
        const float4* r4 = (const float4*)(adj + (size_t)b * NN) + 4 * t;
        float4 v0 = r4[0], v1 = r4[1], v2 = r4[2], v3 = r4[3];
        unsigned m = 0;
        m |= (v0.x > 0.0f) << 0;  m |= (v0.y > 0.0f) << 1;
        m |= (v0.z > 0.0f) << 2;  m |= (v0.w > 0.0f) << 3;
        m |= (v1.x > 0.0f) << 4;  m |= (v1.y > 0.0f) << 5;
        m |= (v1.z > 0.0f) << 6;  m |= (v1.w > 0.0f) << 7;
        m |= (v2.x > 0.0f) << 8;  m |= (v2.y > 0.0f) << 9;
        m |= (v2.z > 0.0f) << 10; m |= (v2.w > 0.0f) << 11;
        m |= (v3.x > 0.0f) << 12; m |= (v3.y > 0.0f) << 13;
        m |= (v3.z > 0.0f) << 14; m |= (v3.w > 0.0f) << 15;
        bitmap[b * 256 + t] = (unsigned short)m;
    } else if (b < NN + 2048) {
        // ---- R = adj_ad @ rel; Abf = bf16(x + R); 2 rows per block ----
        int half = t >> 7;            // 0..1
        int tt = t & 127;
        int i = (b - NN) * 2 + half;
        if (tt < 64) sa[half][tt] = adj_ad[i * 64 + tt];
        __syncthreads();
        float4 acc = make_float4(0.f, 0.f, 0.f, 0.f);
        #pragma unroll 4
        for (int r = 0; r < 64; ++r) {
            float a = sa[half][r];
            float4 rv = ((const float4*)(rel + r * FEAT))[tt];
            acc.x += a * rv.x; acc.y += a * rv.y;
            acc.z += a * rv.z; acc.w += a * rv.w;
        }
        ((float4*)(R + (size_t)i * FEAT))[tt] = acc;
        float4 xv = ((const float4*)(x + (size_t)i * FEAT))[tt];
        ushort4 o;
        o.x = f2bf(acc.x + xv.x); o.y = f2bf(acc.y + xv.y);
        o.z = f2bf(acc.z + xv.z); o.w = f2bf(acc.w + xv.w);
        *(ushort4*)(Abf + (size_t)i * FEAT + 4 * tt) = o;
    } else {
        // ---- weight permutes + f1o/f2o zero ----
        int gid = (b - NN - 2048) * 256 + t;
        if (gid < 262144) {
            int idx = gid;
            int n = idx >> 9, k = idx & 511;
            int h = n >> 6, f = n & 63;
            WcT[idx] = f2bf(Wh[(h * 512 + k) * 64 + f]);
        } else if (gid < 524288) {
            int idx = gid - 262144;
            int n = idx >> 9, k = idx & 511;
            WoT[idx] = f2bf(Wo[k * 512 + n]);
        } else {
            int idx = gid - 524288;          // 0..1023 float4 per array
            ((float4*)f1o)[idx] = make_float4(0.f, 0.f, 0.f, 0.f);
            ((float4*)f2o)[idx] = make_float4(0.f, 0.f, 0.f, 0.f);
        }
    }
}

// ---------------------------------------------------------------------------
// Cbf = A @ Bt^T (bf16 in, fp32 accum, bf16 out) + fused f1/f2 attention dots.
// Extra plane blockIdx.y==8 (layer-1 launch only): bitmap -> CSR expansion
// (independent of the GEMM; hides the serial CSR phase under MFMA blocks).
__global__ __launch_bounds__(256) void gemm_bf16_dot_kernel(
    const bf16_t* __restrict__ A, const bf16_t* __restrict__ Bt,
    unsigned short* __restrict__ Cbf,
    const float* __restrict__ a1, const float* __restrict__ a2,
    float* __restrict__ f1, float* __restrict__ f2, int layer2,
    const unsigned long long* __restrict__ bm64,
    int* __restrict__ deg, int* __restrict__ cols) {
    if (blockIdx.y == 8) {
        // ---- CSR from bitmap: wave wv owns rows bx*64 + wv*16 + rr.
        // Lane l reads u64 word l of the row (bit b -> column 64*l + b).
        int wv = threadIdx.x >> 6, lane = threadIdx.x & 63;
        int row0 = blockIdx.x * 64 + wv * 16;
        unsigned long long w64 = bm64[(size_t)row0 * 64 + lane];
        for (int rr = 0; rr < 16; ++rr) {
            int row = row0 + rr;
            unsigned long long nxt = (rr < 15)
                ? bm64[(size_t)(row + 1) * 64 + lane] : 0ULL;
            int c = __popcll(w64);
            int pre = c;
            #pragma unroll
            for (int off = 1; off < 64; off <<= 1) {
                int n = __shfl_up(pre, off);
                if (lane >= off) pre += n;
            }
            int tot  = __shfl(pre, 63);
            int idx  = pre - c;                    // exclusive prefix
            int* colrow = cols + row * MAXDEG;
            unsigned long long mm = w64;
            while (mm) {
                int bit = __ffsll(mm) - 1;
                mm &= mm - 1;
                if (idx < MAXDEG) colrow[idx] = 64 * lane + bit;
                ++idx;
            }
            if (lane == 0) deg[row] = tot > MAXDEG ? MAXDEG : tot;
            w64 = nxt;
        }
        return;
    }
    __shared__ __align__(16) bf16_t As[64][72];   // pitch 72 elems = 144 B
    __shared__ __align__(16) bf16_t Bs[64][72];
    const int bm = blockIdx.x * 64;
    const int bn = blockIdx.y * 64;
    const int t  = threadIdx.x;
    const int lr = t >> 3;            // 0..31 staging row
    const int lc = (t & 7) * 8;       // staging col (elems)
    const int l  = t & 63;
    const int w  = t >> 6;
    const int mrow = w * 16 + (l & 15);
    const int nrow = l & 15;
    const int q8 = (l >> 4) * 8;

    const bf16_t* Ap0 = A  + (size_t)(bm + lr)      * FEAT + lc;
    const bf16_t* Ap1 = A  + (size_t)(bm + 32 + lr) * FEAT + lc;
    const bf16_t* Bp0 = Bt + (size_t)(bn + lr)      * FEAT + lc;
    const bf16_t* Bp1 = Bt + (size_t)(bn + 32 + lr) * FEAT + lc;
    uint4 ra0 = *(const uint4*)(Ap0);
    uint4 ra1 = *(const uint4*)(Ap1);
    uint4 rb0 = *(const uint4*)(Bp0);
    uint4 rb1 = *(const uint4*)(Bp1);

    f32x4_t acc[4] = {};
    for (int k0 = 0; k0 < FEAT; k0 += 64) {
        *(uint4*)&As[lr][lc]      = ra0;
        *(uint4*)&As[32 + lr][lc] = ra1;
        *(uint4*)&Bs[lr][lc]      = rb0;
        *(uint4*)&Bs[32 + lr][lc] = rb1;
        __syncthreads();
        if (k0 + 64 < FEAT) {
            ra0 = *(const uint4*)(Ap0 + k0 + 64);
            ra1 = *(const uint4*)(Ap1 + k0 + 64);
            rb0 = *(const uint4*)(Bp0 + k0 + 64);
            rb1 = *(const uint4*)(Bp1 + k0 + 64);
        }
        #pragma unroll
        for (int kk = 0; kk < 64; kk += 32) {
            bf16x8_t a = *(const bf16x8_t*)&As[mrow][kk + q8];
            #pragma unroll
            for (int nt = 0; nt < 4; ++nt) {
                bf16x8_t b = *(const bf16x8_t*)&Bs[nt * 16 + nrow][kk + q8];
                acc[nt] = __builtin_amdgcn_mfma_f32_16x16x32_bf16(a, b, acc[nt], 0, 0, 0);
            }
        }
        __syncthreads();
    }
    // C/D layout: col = lane&15, row = (lane>>4)*4 + reg
    const int crow = bm + w * 16 + (l >> 4) * 4;
    const int ccol = bn + (l & 15);
    #pragma unroll
    for (int nt = 0; nt < 4; ++nt)
        #pragma unroll
        for (int r = 0; r < 4; ++r)
            Cbf[(size_t)(crow + r) * FEAT + ccol + nt * 16] = f2bf(acc[nt][r]);

    // fused f1/f2 dots on fp32 accumulators
    float a1v[4], a2v[4];
    #pragma unroll
    for (int nt = 0; nt < 4; ++nt) {
        a1v[nt] = a1[bn + (l & 15) + nt * 16];
        a2v[nt] = a2[bn + (l & 15) + nt * 16];
    }
    float p1[4] = {}, p2[4] = {};
    #pragma unroll
    for (int nt = 0; nt < 4; ++nt)
        #pragma unroll
        for (int r = 0; r < 4; ++r) {
            p1[r] += acc[nt][r] * a1v[nt];
            p2[r] += acc[nt][r] * a2v[nt];
        }
    #pragma unroll
    for (int off = 1; off <= 8; off <<= 1)
        #pragma unroll
        for (int r = 0; r < 4; ++r) {
            p1[r] += __shfl_xor(p1[r], off);
            p2[r] += __shfl_xor(p2[r], off);
        }
    if ((l & 15) == 0) {
        int row = bm + w * 16 + (l >> 4) * 4;
        if (layer2) {
            #pragma unroll
            for (int r = 0; r < 4; ++r) {
                atomicAdd(&f1[row + r], p1[r]);
                atomicAdd(&f2[row + r], p2[r]);
            }
        } else {
            #pragma unroll
            for (int r = 0; r < 4; ++r) {
                f1[blockIdx.y * NN + row + r] = p1[r];
                f2[blockIdx.y * NN + row + r] = p2[r];
            }
        }
    }
}

// ---------------------------------------------------------------------------
// Layer-1 sparse attention + ELU + fused (+R, bf16 cast) epilogue.
__global__ __launch_bounds__(512) void att1_kernel(
    const bf16_t* __restrict__ Hbf, const float* __restrict__ f1,
    const float* __restrict__ f2, const int* __restrict__ deg,
    const int* __restrict__ cols, const float* __restrict__ R,
    bf16_t* __restrict__ outbf) {
    int i = blockIdx.x;
    int tid = threadIdx.x;
    int h = tid >> 6;                 // wave id (phase A: head; phase B: slot)
    int l = tid & 63;
    __shared__ int jl[MAXDEG];
    __shared__ float se[NHEADS][MAXDEG];
    __shared__ float part[NHEADS][FEAT];   // 16 KB
    __shared__ float sinv[NHEADS];
    __shared__ int sdeg;
    if (tid == 0) sdeg = deg[i];
    __syncthreads();
    int d = sdeg;
    int dpad = (d + 31) & ~31;        // multiple of 32 (8 waves x 4 unroll)
    for (int k = tid; k < dpad; k += 512)
        jl[k] = (k < d) ? cols[i * MAXDEG + k] : i;   // pad: self, weight 0
    __syncthreads();
    // ---- phase A: scores for head h ----
    float fi = f1[h * NN + i];
    float lmax = -1e30f;
    for (int k = l; k < d; k += 64) {
        float e = fi + f2[h * NN + jl[k]];
        e = e > 0.0f ? e : ALPHA * e;
        se[h][k] = e;
        lmax = fmaxf(lmax, e);
    }
    for (int off = 32; off; off >>= 1) lmax = fmaxf(lmax, __shfl_down(lmax, off));
    float m = __shfl(lmax, 0);
    float ls = 0.0f;
    for (int k = l; k < d; k += 64) {
        float p = __expf(se[h][k] - m);
        se[h][k] = p;
        ls += p;
    }
    for (int k = d + l; k < dpad; k += 64) se[h][k] = 0.0f;
    for (int off = 32; off; off >>= 1) ls += __shfl_down(ls, off);
    if (l == 0) sinv[h] = 1.0f / ls;
    __syncthreads();                  // se/sinv now read cross-wave
    // ---- phase B: whole-row gather (wave h takes k ≡ h mod 8, unroll 4) ----
    const int myhead = l >> 3;        // head of this lane's output columns
    float acc[8] = {};
    for (int k0 = 0; k0 < dpad; k0 += 32) {
        float pw[4];
        const bf16_t* rp[4];
        #pragma unroll
        for (int j = 0; j < 4; ++j) {
            int k = k0 + j * 8 + h;                  // k < dpad guaranteed
            pw[j] = se[myhead][k];
            rp[j] = Hbf + (size_t)jl[k] * FEAT + l * 8;
        }
        #pragma unroll
        for (int j = 0; j < 4; ++j) {
            us8_t v = *(const us8_t*)rp[j];
            float p = pw[j];
            #pragma unroll
            for (int q = 0; q < 8; ++q) acc[q] += p * bfu2f(v[q]);
        }
    }
    *(float4*)&part[h][l * 8]     = make_float4(acc[0], acc[1], acc[2], acc[3]);
    *(float4*)&part[h][l * 8 + 4] = make_float4(acc[4], acc[5], acc[6], acc[7]);
    __syncthreads();
    // ---- epilogue: thread tid handles output column tid ----
    {
        float sum = 0.0f;
        #pragma unroll
        for (int w2 = 0; w2 < NHEADS; ++w2) sum += part[w2][tid];
        float o = sum * sinv[tid >> 6];
        o = o > 0.0f ? o : __expf(o) - 1.0f;         // ELU
        o += R[(size_t)i * FEAT + tid];
        ((unsigned short*)outbf)[(size_t)i * FEAT + tid] = f2bf(o);
    }
}

// ---------------------------------------------------------------------------
// Layer-2 sparse attention + fused classifier + log_softmax. Block = 256.
__global__ __launch_bounds__(256) void att2_final_kernel(
    const bf16_t* __restrict__ Hbf, const float* __restrict__ f1,
    const float* __restrict__ f2, const int* __restrict__ deg,
    const int* __restrict__ cols, const float* __restrict__ linW,
    const float* __restrict__ linb, float* __restrict__ out) {
    int i = blockIdx.x;
    int t = threadIdx.x;
    __shared__ int jl[MAXDEG];
    __shared__ float sp[MAXDEG];
    __shared__ float red[4];
    __shared__ float part[3][FEAT];
    __shared__ float hrow[FEAT];
    __shared__ float clsred[16][NCLS];
    __shared__ float sl[NCLS];
    __shared__ int sdeg;
    if (t == 0) sdeg = deg[i];
    __syncthreads();
    int d = sdeg;
    int dpad = (d + 15) & ~15;        // multiple of 16 (4 waves x 4 unroll)
    if (t < dpad) jl[t] = (t < d) ? cols[i * MAXDEG + t] : i;
    __syncthreads();
    float e = 0.0f, lmax = -1e30f;
    if (t < d) {
        e = f1[i] + f2[jl[t]];
        e = e > 0.0f ? e : ALPHA * e;
        lmax = e;
    }
    for (int off = 32; off; off >>= 1) lmax = fmaxf(lmax, __shfl_down(lmax, off));
    if ((t & 63) == 0) red[t >> 6] = lmax;
    __syncthreads();
    float m = fmaxf(fmaxf(red[0], red[1]), fmaxf(red[2], red[3]));
    float p = 0.0f;
    if (t < d) p = __expf(e - m);
    if (t < dpad) sp[t] = p;          // pads write 0
    float ls = p;
    for (int off = 32; off; off >>= 1) ls += __shfl_down(ls, off);
    __syncthreads();                  // red[] reads done before overwrite
    if ((t & 63) == 0) red[t >> 6] = ls;
    __syncthreads();                  // publishes sp[] + red[]
    float s = red[0] + red[1] + red[2] + red[3];
    float inv = 1.0f / s;
    // whole-row gather, unroll 4
    const int slot = t >> 6;          // 0..3 (wave id)
    const int cg   = t & 63;          // col group (8 bf16)
    float acc[8] = {};
    for (int k0 = 0; k0 < dpad; k0 += 16) {
        float pw[4];
        const bf16_t* rp[4];
        #pragma unroll
        for (int j = 0; j < 4; ++j) {
            int k = k0 + j * 4 + slot;               // k < dpad guaranteed
            pw[j] = sp[k];
            rp[j] = Hbf + (size_t)jl[k] * FEAT + cg * 8;
        }
        #pragma unroll
        for (int j = 0; j < 4; ++j) {
            us8_t v = *(const us8_t*)rp[j];
            float pk = pw[j];
            #pragma unroll
            for (int q = 0; q < 8; ++q) acc[q] += pk * bfu2f(v[q]);
        }
    }
    // combine slots 1..3 into slot 0; slot 0 publishes h2 row to LDS
    if (slot > 0) {
        float* dst = &part[slot - 1][cg * 8];
        *(float4*)(dst)     = make_float4(acc[0], acc[1], acc[2], acc[3]);
        *(float4*)(dst + 4) = make_float4(acc[4], acc[5], acc[6], acc[7]);
    }
    __syncthreads();
    if (slot == 0) {
        #pragma unroll
        for (int sl2 = 0; sl2 < 3; ++sl2)
            #pragma unroll
            for (int j = 0; j < 8; ++j) acc[j] += part[sl2][cg * 8 + j];
        float* dst = &hrow[cg * 8];
        *(float4*)(dst)     = make_float4(acc[0] * inv, acc[1] * inv, acc[2] * inv, acc[3] * inv);
        *(float4*)(dst + 4) = make_float4(acc[4] * inv, acc[5] * inv, acc[6] * inv, acc[7] * inv);
    }
    __syncthreads();
    // classifier: class c = t&15, segment seg = t>>4 (32 features each)
    {
        int c = t & 15;
        int seg = t >> 4;
        float partial = 0.0f;
        int f0 = seg * 32;
        #pragma unroll 8
        for (int f = f0; f < f0 + 32; ++f) partial += hrow[f] * linW[f * NCLS + c];
        clsred[seg][c] = partial;
    }
    __syncthreads();
    if (t < NCLS) {
        float logit = linb[t];
        #pragma unroll
        for (int seg = 0; seg < 16; ++seg) logit += clsred[seg][t];
        logit = logit > 0.0f ? logit : __expf(logit) - 1.0f;   // ELU
        sl[t] = logit;
    }
    __syncthreads();
    if (t < NCLS) {
        float mm = sl[0];
        #pragma unroll
        for (int c = 1; c < NCLS; ++c) mm = fmaxf(mm, sl[c]);
        float ssum = 0.0f;
        #pragma unroll
        for (int c = 0; c < NCLS; ++c) ssum += __expf(sl[c] - mm);
        out[i * NCLS + t] = sl[t] - mm - logf(ssum);
    }
}

// ---------------------------------------------------------------------------
extern "C" void kernel_launch(void* const* d_in, const int* in_sizes, int n_in,
                              void* d_out, int out_size, void* d_ws, size_t ws_size,
                              hipStream_t stream) {
    const float* x        = (const float*)d_in[0];
    const float* rel      = (const float*)d_in[1];
    // d_in[2] rel_dict: unused (non-math constant per reference)
    const float* adj      = (const float*)d_in[3];
    const float* adj_ad   = (const float*)d_in[4];
    const float* W_heads  = (const float*)d_in[5];
    const float* a1_heads = (const float*)d_in[6];
    const float* a2_heads = (const float*)d_in[7];
    const float* W_out    = (const float*)d_in[8];
    const float* a1_out   = (const float*)d_in[9];
    const float* a2_out   = (const float*)d_in[10];
    const float* lin_W    = (const float*)d_in[11];
    const float* lin_b    = (const float*)d_in[12];
    float* out = (float*)d_out;

    char* ws = (char*)d_ws;
    bf16_t* Abf  = (bf16_t*)(ws);                                 // 4 MB  layer-1 GEMM input
    bf16_t* Abf2 = (bf16_t*)(ws + (4u  << 20));                   // 4 MB  layer-2 GEMM input
    bf16_t* Hbf1 = (bf16_t*)(ws + (8u  << 20));                   // 4 MB  layer-1 H (gather)
    bf16_t* Hbf2 = (bf16_t*)(ws + (12u << 20));                   // 4 MB  layer-2 H (gather)
    float*  R    = (float*) (ws + (16u << 20));                   // 8 MB  adj_ad@rel
    bf16_t* WcT  = (bf16_t*)(ws + (24u << 20));                   // 0.5 MB
    bf16_t* WoT  = (bf16_t*)(ws + (24u << 20) + (512u << 10));    // 0.5 MB
    float*  f1   = (float*) (ws + (25u << 20));                   // 128 KB [8,4096]
    float*  f2   = (float*) (ws + (25u << 20) + (128u << 10));    // 128 KB
    float*  f1o  = (float*) (ws + (25u << 20) + (256u << 10));    // 16 KB
    float*  f2o  = (float*) (ws + (25u << 20) + (272u << 10));    // 16 KB
    int*    deg  = (int*)   (ws + (25u << 20) + (288u << 10));    // 16 KB
    int*    cols = (int*)   (ws + (26u << 20));                   // 2 MB  [4096,128]
    unsigned short* bitmap = (unsigned short*)(ws + (28u << 20)); // 2 MB  [4096,256] u16

    // fused front-end: adj->bitmap (pure stream) + (R, Abf) + weight permutes
    prep_kernel<<<NN + 2048 + 2052, 256, 0, stream>>>(
        adj, bitmap, adj_ad, rel, x, R, Abf,
        W_heads, W_out, (unsigned short*)WcT, (unsigned short*)WoT, f1o, f2o);
    // layer-1 GEMM + fused f1/f2 dots; plane y==8 does bitmap->CSR expansion
    gemm_bf16_dot_kernel<<<dim3(64, 9), 256, 0, stream>>>(
        Abf, WcT, (unsigned short*)Hbf1, a1_heads, a2_heads, f1, f2, 0,
        (const unsigned long long*)bitmap, deg, cols);
    // layer-1 attention + ELU + (+R, bf16) epilogue -> Abf2
    att1_kernel<<<NN, 512, 0, stream>>>(Hbf1, f1, f2, deg, cols, R, Abf2);
    // layer-2 GEMM + fused f1o/f2o dots (atomicAdd across bn blocks)
    gemm_bf16_dot_kernel<<<dim3(64, 8), 256, 0, stream>>>(
        Abf2, WoT, (unsigned short*)Hbf2, a1_out, a2_out, f1o, f2o, 1,
        (const unsigned long long*)bitmap, deg, cols);
    // layer-2 attention + classifier + log_softmax -> out (fused)
    att2_final_kernel<<<NN, 256, 0, stream>>>(Hbf2, f1o, f2o, deg, cols, lin_W, lin_b, out);
}

// Round 13
// 201.628 us; speedup vs baseline: 1.0315x; 1.0315x over previous
//
#include <hip/hip_runtime.h>

#define NN      4096
#define FEAT    512
#define NHID    64
#define NHEADS  8
#define NCLS    16
#define MAXDEG  128
#define ALPHA   0.2f

typedef __bf16 bf16_t;
typedef __bf16 bf16x8_t __attribute__((ext_vector_type(8)));
typedef float  f32x4_t  __attribute__((ext_vector_type(4)));
typedef unsigned short us8_t __attribute__((ext_vector_type(8)));

__device__ inline unsigned short f2bf(float f) {
    unsigned int u = __float_as_uint(f);
    u += 0x7fffu + ((u >> 16) & 1u);          // round-to-nearest-even
    return (unsigned short)(u >> 16);
}
__device__ inline float bfu2f(unsigned short b) {
    return __uint_as_float(((unsigned int)b) << 16);
}

// ---------------------------------------------------------------------------
// Front kernel — deliberately LOW-HBM-traffic (runs while the harness's
// 268 MB ws re-poison fill is still draining HBM; see r12 post-mortem):
//   blocks [0,2048):     R = adj_ad@rel, Abf = bf16(x+R)  (2 rows/block)
//   blocks [2048,4100):  weight permutes + f1o/f2o zero-init
__global__ __launch_bounds__(256) void prep2_kernel(
    const float* __restrict__ adj_ad, const float* __restrict__ rel,
    const float* __restrict__ x, float* __restrict__ R, bf16_t* __restrict__ Abf,
    const float* __restrict__ Wh, const float* __restrict__ Wo,
    unsigned short* __restrict__ WcT, unsigned short* __restrict__ WoT,
    float* __restrict__ f1o, float* __restrict__ f2o) {
    int b = blockIdx.x;
    int t = threadIdx.x;
    __shared__ float sa[2][64];
    if (b < 2048) {
        // ---- R = adj_ad @ rel; Abf = bf16(x + R); 2 rows per block ----
        int half = t >> 7;            // 0..1
        int tt = t & 127;
        int i = b * 2 + half;
        if (tt < 64) sa[half][tt] = adj_ad[i * 64 + tt];
        __syncthreads();
        float4 acc = make_float4(0.f, 0.f, 0.f, 0.f);
        #pragma unroll 4
        for (int r = 0; r < 64; ++r) {
            float a = sa[half][r];
            float4 rv = ((const float4*)(rel + r * FEAT))[tt];
            acc.x += a * rv.x; acc.y += a * rv.y;
            acc.z += a * rv.z; acc.w += a * rv.w;
        }
        ((float4*)(R + (size_t)i * FEAT))[tt] = acc;
        float4 xv = ((const float4*)(x + (size_t)i * FEAT))[tt];
        ushort4 o;
        o.x = f2bf(acc.x + xv.x); o.y = f2bf(acc.y + xv.y);
        o.z = f2bf(acc.z + xv.z); o.w = f2bf(acc.w + xv.w);
        *(ushort4*)(Abf + (size_t)i * FEAT + 4 * tt) = o;
    } else {
        // ---- weight permutes + f1o/f2o zero ----
        int gid = (b - 2048) * 256 + t;
        if (gid < 262144) {
            int idx = gid;
            int n = idx >> 9, k = idx & 511;
            int h = n >> 6, f = n & 63;
            WcT[idx] = f2bf(Wh[(h * 512 + k) * 64 + f]);
        } else if (gid < 524288) {
            int idx = gid - 262144;
            int n = idx >> 9, k = idx & 511;
            WoT[idx] = f2bf(Wo[k * 512 + n]);
        } else {
            int idx = gid - 524288;          // 0..1023 float4 per array
            ((float4*)f1o)[idx] = make_float4(0.f, 0.f, 0.f, 0.f);
            ((float4*)f2o)[idx] = make_float4(0.f, 0.f, 0.f, 0.f);
        }
    }
}

// ---------------------------------------------------------------------------
// CSR build — runs THIRD (latest legal slot before att1), after the harness
// fill has drained, so the 64 MB adj stream gets full HBM bandwidth.
// r10's block prefix-sum compaction (order-independent downstream).
__global__ __launch_bounds__(256) void csr_kernel(
    const float* __restrict__ adj, int* __restrict__ deg, int* __restrict__ cols) {
    int b = blockIdx.x;
    int t = threadIdx.x;
    __shared__ int wsum[4];
    const float4* row4 = (const float4*)(adj + (size_t)b * NN);
    float4 v0 = row4[t];
    float4 v1 = row4[t + 256];
    float4 v2 = row4[t + 512];
    float4 v3 = row4[t + 768];
    unsigned mask = 0;
    mask |= (v0.x > 0.0f) << 0;  mask |= (v0.y > 0.0f) << 1;
    mask |= (v0.z > 0.0f) << 2;  mask |= (v0.w > 0.0f) << 3;
    mask |= (v1.x > 0.0f) << 4;  mask |= (v1.y > 0.0f) << 5;
    mask |= (v1.z > 0.0f) << 6;  mask |= (v1.w > 0.0f) << 7;
    mask |= (v2.x > 0.0f) << 8;  mask |= (v2.y > 0.0f) << 9;
    mask |= (v2.z > 0.0f) << 10; mask |= (v2.w > 0.0f) << 11;
    mask |= (v3.x > 0.0f) << 12; mask |= (v3.y > 0.0f) << 13;
    mask |= (v3.z > 0.0f) << 14; mask |= (v3.w > 0.0f) << 15;
    int c = __popc(mask);
    int lane = t & 63;
    int pre = c;
    #pragma unroll
    for (int off = 1; off < 64; off <<= 1) {
        int n = __shfl_up(pre, off);
        if (lane >= off) pre += n;
    }
    if (lane == 63) wsum[t >> 6] = pre;
    __syncthreads();
    int base = pre - c;                      // exclusive within wave
    #pragma unroll
    for (int w2 = 0; w2 < 4; ++w2)
        if (w2 < (t >> 6)) base += wsum[w2];
    int* colrow = cols + b * MAXDEG;
    unsigned mm = mask;
    int idx = base;
    while (mm) {
        int bit = __ffs(mm) - 1;
        mm &= mm - 1;
        int j = 4 * t + (bit >> 2) * 1024 + (bit & 3);
        if (idx < MAXDEG) colrow[idx] = j;
        ++idx;
    }
    if (t == 0) {
        int tot = wsum[0] + wsum[1] + wsum[2] + wsum[3];
        deg[b] = tot > MAXDEG ? MAXDEG : tot;
    }
}

// ---------------------------------------------------------------------------
// Cbf = A @ Bt^T (bf16 in, fp32 accum, bf16 out) + fused f1/f2 attention dots.
// Register double-buffer on the global staging loads.
__global__ __launch_bounds__(256) void gemm_bf16_dot_kernel(
    const bf16_t* __restrict__ A, const bf16_t* __restrict__ Bt,
    unsigned short* __restrict__ Cbf,
    const float* __restrict__ a1, const float* __restrict__ a2,
    float* __restrict__ f1, float* __restrict__ f2, int layer2) {
    __shared__ __align__(16) bf16_t As[64][72];   // pitch 72 elems = 144 B
    __shared__ __align__(16) bf16_t Bs[64][72];
    const int bm = blockIdx.x * 64;
    const int bn = blockIdx.y * 64;
    const int t  = threadIdx.x;
    const int lr = t >> 3;            // 0..31 staging row
    const int lc = (t & 7) * 8;       // staging col (elems)
    const int l  = t & 63;
    const int w  = t >> 6;
    const int mrow = w * 16 + (l & 15);
    const int nrow = l & 15;
    const int q8 = (l >> 4) * 8;

    const bf16_t* Ap0 = A  + (size_t)(bm + lr)      * FEAT + lc;
    const bf16_t* Ap1 = A  + (size_t)(bm + 32 + lr) * FEAT + lc;
    const bf16_t* Bp0 = Bt + (size_t)(bn + lr)      * FEAT + lc;
    const bf16_t* Bp1 = Bt + (size_t)(bn + 32 + lr) * FEAT + lc;
    uint4 ra0 = *(const uint4*)(Ap0);
    uint4 ra1 = *(const uint4*)(Ap1);
    uint4 rb0 = *(const uint4*)(Bp0);
    uint4 rb1 = *(const uint4*)(Bp1);

    f32x4_t acc[4] = {};
    for (int k0 = 0; k0 < FEAT; k0 += 64) {
        *(uint4*)&As[lr][lc]      = ra0;
        *(uint4*)&As[32 + lr][lc] = ra1;
        *(uint4*)&Bs[lr][lc]      = rb0;
        *(uint4*)&Bs[32 + lr][lc] = rb1;
        __syncthreads();
        if (k0 + 64 < FEAT) {
            ra0 = *(const uint4*)(Ap0 + k0 + 64);
            ra1 = *(const uint4*)(Ap1 + k0 + 64);
            rb0 = *(const uint4*)(Bp0 + k0 + 64);
            rb1 = *(const uint4*)(Bp1 + k0 + 64);
        }
        #pragma unroll
        for (int kk = 0; kk < 64; kk += 32) {
            bf16x8_t a = *(const bf16x8_t*)&As[mrow][kk + q8];
            #pragma unroll
            for (int nt = 0; nt < 4; ++nt) {
                bf16x8_t b = *(const bf16x8_t*)&Bs[nt * 16 + nrow][kk + q8];
                acc[nt] = __builtin_amdgcn_mfma_f32_16x16x32_bf16(a, b, acc[nt], 0, 0, 0);
            }
        }
        __syncthreads();
    }
    // C/D layout: col = lane&15, row = (lane>>4)*4 + reg
    const int crow = bm + w * 16 + (l >> 4) * 4;
    const int ccol = bn + (l & 15);
    #pragma unroll
    for (int nt = 0; nt < 4; ++nt)
        #pragma unroll
        for (int r = 0; r < 4; ++r)
            Cbf[(size_t)(crow + r) * FEAT + ccol + nt * 16] = f2bf(acc[nt][r]);

    // fused f1/f2 dots on fp32 accumulators
    float a1v[4], a2v[4];
    #pragma unroll
    for (int nt = 0; nt < 4; ++nt) {
        a1v[nt] = a1[bn + (l & 15) + nt * 16];
        a2v[nt] = a2[bn + (l & 15) + nt * 16];
    }
    float p1[4] = {}, p2[4] = {};
    #pragma unroll
    for (int nt = 0; nt < 4; ++nt)
        #pragma unroll
        for (int r = 0; r < 4; ++r) {
            p1[r] += acc[nt][r] * a1v[nt];
            p2[r] += acc[nt][r] * a2v[nt];
        }
    #pragma unroll
    for (int off = 1; off <= 8; off <<= 1)
        #pragma unroll
        for (int r = 0; r < 4; ++r) {
            p1[r] += __shfl_xor(p1[r], off);
            p2[r] += __shfl_xor(p2[r], off);
        }
    if ((l & 15) == 0) {
        int row = bm + w * 16 + (l >> 4) * 4;
        if (layer2) {
            #pragma unroll
            for (int r = 0; r < 4; ++r) {
                atomicAdd(&f1[row + r], p1[r]);
                atomicAdd(&f2[row + r], p2[r]);
            }
        } else {
            #pragma unroll
            for (int r = 0; r < 4; ++r) {
                f1[blockIdx.y * NN + row + r] = p1[r];
                f2[blockIdx.y * NN + row + r] = p2[r];
            }
        }
    }
}

// ---------------------------------------------------------------------------
// Layer-1 sparse attention + ELU + fused (+R, bf16 cast) epilogue.
__global__ __launch_bounds__(512) void att1_kernel(
    const bf16_t* __restrict__ Hbf, const float* __restrict__ f1,
    const float* __restrict__ f2, const int* __restrict__ deg,
    const int* __restrict__ cols, const float* __restrict__ R,
    bf16_t* __restrict__ outbf) {
    int i = blockIdx.x;
    int tid = threadIdx.x;
    int h = tid >> 6;                 // wave id (phase A: head; phase B: slot)
    int l = tid & 63;
    __shared__ int jl[MAXDEG];
    __shared__ float se[NHEADS][MAXDEG];
    __shared__ float part[NHEADS][FEAT];   // 16 KB
    __shared__ float sinv[NHEADS];
    __shared__ int sdeg;
    if (tid == 0) sdeg = deg[i];
    __syncthreads();
    int d = sdeg;
    int dpad = (d + 31) & ~31;        // multiple of 32 (8 waves x 4 unroll)
    for (int k = tid; k < dpad; k += 512)
        jl[k] = (k < d) ? cols[i * MAXDEG + k] : i;   // pad: self, weight 0
    __syncthreads();
    // ---- phase A: scores for head h ----
    float fi = f1[h * NN + i];
    float lmax = -1e30f;
    for (int k = l; k < d; k += 64) {
        float e = fi + f2[h * NN + jl[k]];
        e = e > 0.0f ? e : ALPHA * e;
        se[h][k] = e;
        lmax = fmaxf(lmax, e);
    }
    for (int off = 32; off; off >>= 1) lmax = fmaxf(lmax, __shfl_down(lmax, off));
    float m = __shfl(lmax, 0);
    float ls = 0.0f;
    for (int k = l; k < d; k += 64) {
        float p = __expf(se[h][k] - m);
        se[h][k] = p;
        ls += p;
    }
    for (int k = d + l; k < dpad; k += 64) se[h][k] = 0.0f;
    for (int off = 32; off; off >>= 1) ls += __shfl_down(ls, off);
    if (l == 0) sinv[h] = 1.0f / ls;
    __syncthreads();                  // se/sinv now read cross-wave
    // ---- phase B: whole-row gather (wave h takes k ≡ h mod 8, unroll 4) ----
    const int myhead = l >> 3;        // head of this lane's output columns
    float acc[8] = {};
    for (int k0 = 0; k0 < dpad; k0 += 32) {
        float pw[4];
        const bf16_t* rp[4];
        #pragma unroll
        for (int j = 0; j < 4; ++j) {
            int k = k0 + j * 8 + h;                  // k < dpad guaranteed
            pw[j] = se[myhead][k];
            rp[j] = Hbf + (size_t)jl[k] * FEAT + l * 8;
        }
        #pragma unroll
        for (int j = 0; j < 4; ++j) {
            us8_t v = *(const us8_t*)rp[j];
            float p = pw[j];
            #pragma unroll
            for (int q = 0; q < 8; ++q) acc[q] += p * bfu2f(v[q]);
        }
    }
    *(float4*)&part[h][l * 8]     = make_float4(acc[0], acc[1], acc[2], acc[3]);
    *(float4*)&part[h][l * 8 + 4] = make_float4(acc[4], acc[5], acc[6], acc[7]);
    __syncthreads();
    // ---- epilogue: thread tid handles output column tid ----
    {
        float sum = 0.0f;
        #pragma unroll
        for (int w2 = 0; w2 < NHEADS; ++w2) sum += part[w2][tid];
        float o = sum * sinv[tid >> 6];
        o = o > 0.0f ? o : __expf(o) - 1.0f;         // ELU
        o += R[(size_t)i * FEAT + tid];
        ((unsigned short*)outbf)[(size_t)i * FEAT + tid] = f2bf(o);
    }
}

// ---------------------------------------------------------------------------
// Layer-2 sparse attention + fused classifier + log_softmax. Block = 256.
__global__ __launch_bounds__(256) void att2_final_kernel(
    const bf16_t* __restrict__ Hbf, const float* __restrict__ f1,
    const float* __restrict__ f2, const int* __restrict__ deg,
    const int* __restrict__ cols, const float* __restrict__ linW,
    const float* __restrict__ linb, float* __restrict__ out) {
    int i = blockIdx.x;
    int t = threadIdx.x;
    __shared__ int jl[MAXDEG];
    __shared__ float sp[MAXDEG];
    __shared__ float red[4];
    __shared__ float part[3][FEAT];
    __shared__ float hrow[FEAT];
    __shared__ float clsred[16][NCLS];
    __shared__ float sl[NCLS];
    __shared__ int sdeg;
    if (t == 0) sdeg = deg[i];
    __syncthreads();
    int d = sdeg;
    int dpad = (d + 15) & ~15;        // multiple of 16 (4 waves x 4 unroll)
    if (t < dpad) jl[t] = (t < d) ? cols[i * MAXDEG + t] : i;
    __syncthreads();
    float e = 0.0f, lmax = -1e30f;
    if (t < d) {
        e = f1[i] + f2[jl[t]];
        e = e > 0.0f ? e : ALPHA * e;
        lmax = e;
    }
    for (int off = 32; off; off >>= 1) lmax = fmaxf(lmax, __shfl_down(lmax, off));
    if ((t & 63) == 0) red[t >> 6] = lmax;
    __syncthreads();
    float m = fmaxf(fmaxf(red[0], red[1]), fmaxf(red[2], red[3]));
    float p = 0.0f;
    if (t < d) p = __expf(e - m);
    if (t < dpad) sp[t] = p;          // pads write 0
    float ls = p;
    for (int off = 32; off; off >>= 1) ls += __shfl_down(ls, off);
    __syncthreads();                  // red[] reads done before overwrite
    if ((t & 63) == 0) red[t >> 6] = ls;
    __syncthreads();                  // publishes sp[] + red[]
    float s = red[0] + red[1] + red[2] + red[3];
    float inv = 1.0f / s;
    // whole-row gather, unroll 4
    const int slot = t >> 6;          // 0..3 (wave id)
    const int cg   = t & 63;          // col group (8 bf16)
    float acc[8] = {};
    for (int k0 = 0; k0 < dpad; k0 += 16) {
        float pw[4];
        const bf16_t* rp[4];
        #pragma unroll
        for (int j = 0; j < 4; ++j) {
            int k = k0 + j * 4 + slot;               // k < dpad guaranteed
            pw[j] = sp[k];
            rp[j] = Hbf + (size_t)jl[k] * FEAT + cg * 8;
        }
        #pragma unroll
        for (int j = 0; j < 4; ++j) {
            us8_t v = *(const us8_t*)rp[j];
            float pk = pw[j];
            #pragma unroll
            for (int q = 0; q < 8; ++q) acc[q] += pk * bfu2f(v[q]);
        }
    }
    // combine slots 1..3 into slot 0; slot 0 publishes h2 row to LDS
    if (slot > 0) {
        float* dst = &part[slot - 1][cg * 8];
        *(float4*)(dst)     = make_float4(acc[0], acc[1], acc[2], acc[3]);
        *(float4*)(dst + 4) = make_float4(acc[4], acc[5], acc[6], acc[7]);
    }
    __syncthreads();
    if (slot == 0) {
        #pragma unroll
        for (int sl2 = 0; sl2 < 3; ++sl2)
            #pragma unroll
            for (int j = 0; j < 8; ++j) acc[j] += part[sl2][cg * 8 + j];
        float* dst = &hrow[cg * 8];
        *(float4*)(dst)     = make_float4(acc[0] * inv, acc[1] * inv, acc[2] * inv, acc[3] * inv);
        *(float4*)(dst + 4) = make_float4(acc[4] * inv, acc[5] * inv, acc[6] * inv, acc[7] * inv);
    }
    __syncthreads();
    // classifier: class c = t&15, segment seg = t>>4 (32 features each)
    {
        int c = t & 15;
        int seg = t >> 4;
        float partial = 0.0f;
        int f0 = seg * 32;
        #pragma unroll 8
        for (int f = f0; f < f0 + 32; ++f) partial += hrow[f] * linW[f * NCLS + c];
        clsred[seg][c] = partial;
    }
    __syncthreads();
    if (t < NCLS) {
        float logit = linb[t];
        #pragma unroll
        for (int seg = 0; seg < 16; ++seg) logit += clsred[seg][t];
        logit = logit > 0.0f ? logit : __expf(logit) - 1.0f;   // ELU
        sl[t] = logit;
    }
    __syncthreads();
    if (t < NCLS) {
        float mm = sl[0];
        #pragma unroll
        for (int c = 1; c < NCLS; ++c) mm = fmaxf(mm, sl[c]);
        float ssum = 0.0f;
        #pragma unroll
        for (int c = 0; c < NCLS; ++c) ssum += __expf(sl[c] - mm);
        out[i * NCLS + t] = sl[t] - mm - logf(ssum);
    }
}

// ---------------------------------------------------------------------------
extern "C" void kernel_launch(void* const* d_in, const int* in_sizes, int n_in,
                              void* d_out, int out_size, void* d_ws, size_t ws_size,
                              hipStream_t stream) {
    const float* x        = (const float*)d_in[0];
    const float* rel      = (const float*)d_in[1];
    // d_in[2] rel_dict: unused (non-math constant per reference)
    const float* adj      = (const float*)d_in[3];
    const float* adj_ad   = (const float*)d_in[4];
    const float* W_heads  = (const float*)d_in[5];
    const float* a1_heads = (const float*)d_in[6];
    const float* a2_heads = (const float*)d_in[7];
    const float* W_out    = (const float*)d_in[8];
    const float* a1_out   = (const float*)d_in[9];
    const float* a2_out   = (const float*)d_in[10];
    const float* lin_W    = (const float*)d_in[11];
    const float* lin_b    = (const float*)d_in[12];
    float* out = (float*)d_out;

    char* ws = (char*)d_ws;
    bf16_t* Abf  = (bf16_t*)(ws);                                 // 4 MB  layer-1 GEMM input
    bf16_t* Abf2 = (bf16_t*)(ws + (4u  << 20));                   // 4 MB  layer-2 GEMM input
    bf16_t* Hbf1 = (bf16_t*)(ws + (8u  << 20));                   // 4 MB  layer-1 H (gather)
    bf16_t* Hbf2 = (bf16_t*)(ws + (12u << 20));                   // 4 MB  layer-2 H (gather)
    float*  R    = (float*) (ws + (16u << 20));                   // 8 MB  adj_ad@rel
    bf16_t* WcT  = (bf16_t*)(ws + (24u << 20));                   // 0.5 MB
    bf16_t* WoT  = (bf16_t*)(ws + (24u << 20) + (512u << 10));    // 0.5 MB
    float*  f1   = (float*) (ws + (25u << 20));                   // 128 KB [8,4096]
    float*  f2   = (float*) (ws + (25u << 20) + (128u << 10));    // 128 KB
    float*  f1o  = (float*) (ws + (25u << 20) + (256u << 10));    // 16 KB
    float*  f2o  = (float*) (ws + (25u << 20) + (272u << 10));    // 16 KB
    int*    deg  = (int*)   (ws + (25u << 20) + (288u << 10));    // 16 KB
    int*    cols = (int*)   (ws + (26u << 20));                   // 2 MB  [4096,128]

    // 1. low-traffic front: (R, Abf) + weight permutes + f-zero
    prep2_kernel<<<2048 + 2052, 256, 0, stream>>>(
        adj_ad, rel, x, R, Abf,
        W_heads, W_out, (unsigned short*)WcT, (unsigned short*)WoT, f1o, f2o);
    // 2. layer-1 GEMM + fused f1/f2 dots (mostly L2-resident traffic)
    gemm_bf16_dot_kernel<<<dim3(64, 8), 256, 0, stream>>>(
        Abf, WcT, (unsigned short*)Hbf1, a1_heads, a2_heads, f1, f2, 0);
    // 3. adjacency -> capped CSR (64 MB scan, now past the harness fill drain)
    csr_kernel<<<NN, 256, 0, stream>>>(adj, deg, cols);
    // 4. layer-1 attention + ELU + (+R, bf16) epilogue -> Abf2
    att1_kernel<<<NN, 512, 0, stream>>>(Hbf1, f1, f2, deg, cols, R, Abf2);
    // 5. layer-2 GEMM + fused f1o/f2o dots (atomicAdd across bn blocks)
    gemm_bf16_dot_kernel<<<dim3(64, 8), 256, 0, stream>>>(
        Abf2, WoT, (unsigned short*)Hbf2, a1_out, a2_out, f1o, f2o, 1);
    // 6. layer-2 attention + classifier + log_softmax -> out (fused)
    att2_final_kernel<<<NN, 256, 0, stream>>>(Hbf2, f1o, f2o, deg, cols, lin_W, lin_b, out);
}

// Round 14
// 195.967 us; speedup vs baseline: 1.0613x; 1.0289x over previous
//
#include <hip/hip_runtime.h>

#define NN      4096
#define FEAT    512
#define NHID    64
#define NHEADS  8
#define NCLS    16
#define MAXDEG  128
#define ALPHA   0.2f

typedef __bf16 bf16_t;
typedef __bf16 bf16x8_t __attribute__((ext_vector_type(8)));
typedef float  f32x4_t  __attribute__((ext_vector_type(4)));
typedef unsigned short us8_t __attribute__((ext_vector_type(8)));

__device__ inline unsigned short f2bf(float f) {
    unsigned int u = __float_as_uint(f);
    u += 0x7fffu + ((u >> 16) & 1u);          // round-to-nearest-even
    return (unsigned short)(u >> 16);
}
__device__ inline float bfu2f(unsigned short b) {
    return __uint_as_float(((unsigned int)b) << 16);
}

// ---------------------------------------------------------------------------
// Fused front-end (one launch, 8196 blocks of 256) — r10-best arrangement:
// the 64 MB adj scan deliberately CO-RUNS with the harness's ws re-poison
// fill drain (see r12/r13 post-mortems: serializing it after other work
// regressed 7-13 µs).
//   blocks [0,4096):     CSR build of adj row b (block prefix-sum compaction)
//   blocks [4096,6144):  Rbf = bf16(adj_ad@rel), Abf = bf16(x+R)  (2 rows/blk)
//   blocks [6144,8196):  weight permutes + f1o/f2o zero-init
__global__ __launch_bounds__(256) void prep_kernel(
    const float* __restrict__ adj, int* __restrict__ deg, int* __restrict__ cols,
    const float* __restrict__ adj_ad, const float* __restrict__ rel,
    const float* __restrict__ x, unsigned short* __restrict__ Rbf,
    bf16_t* __restrict__ Abf,
    const float* __restrict__ Wh, const float* __restrict__ Wo,
    unsigned short* __restrict__ WcT, unsigned short* __restrict__ WoT,
    float* __restrict__ f1o, float* __restrict__ f2o) {
    int b = blockIdx.x;
    int t = threadIdx.x;
    __shared__ int wsum[4];
    __shared__ float sa[2][64];
    if (b < NN) {
        // ---- CSR via load-all + prefix-sum compaction.
        // Thread t owns float4s {t, t+256, t+512, t+768}; cols order is
        // thread-interleaved — downstream softmax/accum are order-indep.
        const float4* row4 = (const float4*)(adj + (size_t)b * NN);
        float4 v0 = row4[t];
        float4 v1 = row4[t + 256];
        float4 v2 = row4[t + 512];
        float4 v3 = row4[t + 768];
        unsigned mask = 0;
        mask |= (v0.x > 0.0f) << 0;  mask |= (v0.y > 0.0f) << 1;
        mask |= (v0.z > 0.0f) << 2;  mask |= (v0.w > 0.0f) << 3;
        mask |= (v1.x > 0.0f) << 4;  mask |= (v1.y > 0.0f) << 5;
        mask |= (v1.z > 0.0f) << 6;  mask |= (v1.w > 0.0f) << 7;
        mask |= (v2.x > 0.0f) << 8;  mask |= (v2.y > 0.0f) << 9;
        mask |= (v2.z > 0.0f) << 10; mask |= (v2.w > 0.0f) << 11;
        mask |= (v3.x > 0.0f) << 12; mask |= (v3.y > 0.0f) << 13;
        mask |= (v3.z > 0.0f) << 14; mask |= (v3.w > 0.0f) << 15;
        int c = __popc(mask);
        int lane = t & 63;
        int pre = c;
        #pragma unroll
        for (int off = 1; off < 64; off <<= 1) {
            int n = __shfl_up(pre, off);
            if (lane >= off) pre += n;
        }
        if (lane == 63) wsum[t >> 6] = pre;
        __syncthreads();
        int base = pre - c;                      // exclusive within wave
        #pragma unroll
        for (int w2 = 0; w2 < 4; ++w2)
            if (w2 < (t >> 6)) base += wsum[w2];
        int* colrow = cols + b * MAXDEG;
        unsigned mm = mask;
        int idx = base;
        while (mm) {
            int bit = __ffs(mm) - 1;
            mm &= mm - 1;
            int j = 4 * t + (bit >> 2) * 1024 + (bit & 3);
            if (idx < MAXDEG) colrow[idx] = j;
            ++idx;
        }
        if (t == 0) {
            int tot = wsum[0] + wsum[1] + wsum[2] + wsum[3];
            deg[b] = tot > MAXDEG ? MAXDEG : tot;
        }
    } else if (b < NN + 2048) {
        // ---- R = adj_ad @ rel (bf16 store); Abf = bf16(x + R) ----
        int half = t >> 7;            // 0..1
        int tt = t & 127;
        int i = (b - NN) * 2 + half;
        if (tt < 64) sa[half][tt] = adj_ad[i * 64 + tt];
        __syncthreads();
        float4 acc = make_float4(0.f, 0.f, 0.f, 0.f);
        #pragma unroll 4
        for (int r = 0; r < 64; ++r) {
            float a = sa[half][r];
            float4 rv = ((const float4*)(rel + r * FEAT))[tt];
            acc.x += a * rv.x; acc.y += a * rv.y;
            acc.z += a * rv.z; acc.w += a * rv.w;
        }
        ushort4 rb;
        rb.x = f2bf(acc.x); rb.y = f2bf(acc.y);
        rb.z = f2bf(acc.z); rb.w = f2bf(acc.w);
        *(ushort4*)(Rbf + (size_t)i * FEAT + 4 * tt) = rb;
        float4 xv = ((const float4*)(x + (size_t)i * FEAT))[tt];
        ushort4 o;
        o.x = f2bf(acc.x + xv.x); o.y = f2bf(acc.y + xv.y);
        o.z = f2bf(acc.z + xv.z); o.w = f2bf(acc.w + xv.w);
        *(ushort4*)(Abf + (size_t)i * FEAT + 4 * tt) = o;
    } else {
        // ---- weight permutes + f1o/f2o zero ----
        int gid = (b - NN - 2048) * 256 + t;
        if (gid < 262144) {
            int idx = gid;
            int n = idx >> 9, k = idx & 511;
            int h = n >> 6, f = n & 63;
            WcT[idx] = f2bf(Wh[(h * 512 + k) * 64 + f]);
        } else if (gid < 524288) {
            int idx = gid - 262144;
            int n = idx >> 9, k = idx & 511;
            WoT[idx] = f2bf(Wo[k * 512 + n]);
        } else {
            int idx = gid - 524288;          // 0..1023 float4 per array
            ((float4*)f1o)[idx] = make_float4(0.f, 0.f, 0.f, 0.f);
            ((float4*)f2o)[idx] = make_float4(0.f, 0.f, 0.f, 0.f);
        }
    }
}

// ---------------------------------------------------------------------------
// Cbf = A @ Bt^T (bf16 in, fp32 accum, bf16 out) + fused f1/f2 attention dots.
// Register double-buffer: K-tile k+1 global loads issue right after the
// barrier, overlapping the MFMA loop of tile k.
__global__ __launch_bounds__(256) void gemm_bf16_dot_kernel(
    const bf16_t* __restrict__ A, const bf16_t* __restrict__ Bt,
    unsigned short* __restrict__ Cbf,
    const float* __restrict__ a1, const float* __restrict__ a2,
    float* __restrict__ f1, float* __restrict__ f2, int layer2) {
    __shared__ __align__(16) bf16_t As[64][72];   // pitch 72 elems = 144 B
    __shared__ __align__(16) bf16_t Bs[64][72];
    const int bm = blockIdx.x * 64;
    const int bn = blockIdx.y * 64;
    const int t  = threadIdx.x;
    const int lr = t >> 3;            // 0..31 staging row
    const int lc = (t & 7) * 8;       // staging col (elems)
    const int l  = t & 63;
    const int w  = t >> 6;
    const int mrow = w * 16 + (l & 15);
    const int nrow = l & 15;
    const int q8 = (l >> 4) * 8;

    const bf16_t* Ap0 = A  + (size_t)(bm + lr)      * FEAT + lc;
    const bf16_t* Ap1 = A  + (size_t)(bm + 32 + lr) * FEAT + lc;
    const bf16_t* Bp0 = Bt + (size_t)(bn + lr)      * FEAT + lc;
    const bf16_t* Bp1 = Bt + (size_t)(bn + 32 + lr) * FEAT + lc;
    uint4 ra0 = *(const uint4*)(Ap0);
    uint4 ra1 = *(const uint4*)(Ap1);
    uint4 rb0 = *(const uint4*)(Bp0);
    uint4 rb1 = *(const uint4*)(Bp1);

    f32x4_t acc[4] = {};
    for (int k0 = 0; k0 < FEAT; k0 += 64) {
        *(uint4*)&As[lr][lc]      = ra0;
        *(uint4*)&As[32 + lr][lc] = ra1;
        *(uint4*)&Bs[lr][lc]      = rb0;
        *(uint4*)&Bs[32 + lr][lc] = rb1;
        __syncthreads();
        if (k0 + 64 < FEAT) {
            ra0 = *(const uint4*)(Ap0 + k0 + 64);
            ra1 = *(const uint4*)(Ap1 + k0 + 64);
            rb0 = *(const uint4*)(Bp0 + k0 + 64);
            rb1 = *(const uint4*)(Bp1 + k0 + 64);
        }
        #pragma unroll
        for (int kk = 0; kk < 64; kk += 32) {
            bf16x8_t a = *(const bf16x8_t*)&As[mrow][kk + q8];
            #pragma unroll
            for (int nt = 0; nt < 4; ++nt) {
                bf16x8_t b = *(const bf16x8_t*)&Bs[nt * 16 + nrow][kk + q8];
                acc[nt] = __builtin_amdgcn_mfma_f32_16x16x32_bf16(a, b, acc[nt], 0, 0, 0);
            }
        }
        __syncthreads();
    }
    // C/D layout: col = lane&15, row = (lane>>4)*4 + reg
    const int crow = bm + w * 16 + (l >> 4) * 4;
    const int ccol = bn + (l & 15);
    #pragma unroll
    for (int nt = 0; nt < 4; ++nt)
        #pragma unroll
        for (int r = 0; r < 4; ++r)
            Cbf[(size_t)(crow + r) * FEAT + ccol + nt * 16] = f2bf(acc[nt][r]);

    // fused f1/f2 dots on fp32 accumulators
    float a1v[4], a2v[4];
    #pragma unroll
    for (int nt = 0; nt < 4; ++nt) {
        a1v[nt] = a1[bn + (l & 15) + nt * 16];
        a2v[nt] = a2[bn + (l & 15) + nt * 16];
    }
    float p1[4] = {}, p2[4] = {};
    #pragma unroll
    for (int nt = 0; nt < 4; ++nt)
        #pragma unroll
        for (int r = 0; r < 4; ++r) {
            p1[r] += acc[nt][r] * a1v[nt];
            p2[r] += acc[nt][r] * a2v[nt];
        }
    #pragma unroll
    for (int off = 1; off <= 8; off <<= 1)
        #pragma unroll
        for (int r = 0; r < 4; ++r) {
            p1[r] += __shfl_xor(p1[r], off);
            p2[r] += __shfl_xor(p2[r], off);
        }
    if ((l & 15) == 0) {
        int row = bm + w * 16 + (l >> 4) * 4;
        if (layer2) {
            #pragma unroll
            for (int r = 0; r < 4; ++r) {
                atomicAdd(&f1[row + r], p1[r]);
                atomicAdd(&f2[row + r], p2[r]);
            }
        } else {
            #pragma unroll
            for (int r = 0; r < 4; ++r) {
                f1[blockIdx.y * NN + row + r] = p1[r];
                f2[blockIdx.y * NN + row + r] = p2[r];
            }
        }
    }
}

// ---------------------------------------------------------------------------
// Layer-1 sparse attention + ELU + fused (+R, bf16 cast) epilogue.
__global__ __launch_bounds__(512) void att1_kernel(
    const bf16_t* __restrict__ Hbf, const float* __restrict__ f1,
    const float* __restrict__ f2, const int* __restrict__ deg,
    const int* __restrict__ cols, const unsigned short* __restrict__ Rbf,
    bf16_t* __restrict__ outbf) {
    int i = blockIdx.x;
    int tid = threadIdx.x;
    int h = tid >> 6;                 // wave id (phase A: head; phase B: slot)
    int l = tid & 63;
    __shared__ int jl[MAXDEG];
    __shared__ float se[NHEADS][MAXDEG];
    __shared__ float part[NHEADS][FEAT];   // 16 KB
    __shared__ float sinv[NHEADS];
    __shared__ int sdeg;
    if (tid == 0) sdeg = deg[i];
    __syncthreads();
    int d = sdeg;
    int dpad = (d + 31) & ~31;        // multiple of 32 (8 waves x 4 unroll)
    for (int k = tid; k < dpad; k += 512)
        jl[k] = (k < d) ? cols[i * MAXDEG + k] : i;   // pad: self, weight 0
    __syncthreads();
    // ---- phase A: scores for head h ----
    float fi = f1[h * NN + i];
    float lmax = -1e30f;
    for (int k = l; k < d; k += 64) {
        float e = fi + f2[h * NN + jl[k]];
        e = e > 0.0f ? e : ALPHA * e;
        se[h][k] = e;
        lmax = fmaxf(lmax, e);
    }
    for (int off = 32; off; off >>= 1) lmax = fmaxf(lmax, __shfl_down(lmax, off));
    float m = __shfl(lmax, 0);
    float ls = 0.0f;
    for (int k = l; k < d; k += 64) {
        float p = __expf(se[h][k] - m);
        se[h][k] = p;
        ls += p;
    }
    for (int k = d + l; k < dpad; k += 64) se[h][k] = 0.0f;
    for (int off = 32; off; off >>= 1) ls += __shfl_down(ls, off);
    if (l == 0) sinv[h] = 1.0f / ls;
    __syncthreads();                  // se/sinv now read cross-wave
    // ---- phase B: whole-row gather (wave h takes k ≡ h mod 8, unroll 4) ----
    const int myhead = l >> 3;        // head of this lane's output columns
    float acc[8] = {};
    for (int k0 = 0; k0 < dpad; k0 += 32) {
        float pw[4];
        const bf16_t* rp[4];
        #pragma unroll
        for (int j = 0; j < 4; ++j) {
            int k = k0 + j * 8 + h;                  // k < dpad guaranteed
            pw[j] = se[myhead][k];
            rp[j] = Hbf + (size_t)jl[k] * FEAT + l * 8;
        }
        #pragma unroll
        for (int j = 0; j < 4; ++j) {
            us8_t v = *(const us8_t*)rp[j];
            float p = pw[j];
            #pragma unroll
            for (int q = 0; q < 8; ++q) acc[q] += p * bfu2f(v[q]);
        }
    }
    *(float4*)&part[h][l * 8]     = make_float4(acc[0], acc[1], acc[2], acc[3]);
    *(float4*)&part[h][l * 8 + 4] = make_float4(acc[4], acc[5], acc[6], acc[7]);
    __syncthreads();
    // ---- epilogue: thread tid handles output column tid ----
    {
        float sum = 0.0f;
        #pragma unroll
        for (int w2 = 0; w2 < NHEADS; ++w2) sum += part[w2][tid];
        float o = sum * sinv[tid >> 6];
        o = o > 0.0f ? o : __expf(o) - 1.0f;         // ELU
        o += bfu2f(Rbf[(size_t)i * FEAT + tid]);     // bf16 residual (r13 micro)
        ((unsigned short*)outbf)[(size_t)i * FEAT + tid] = f2bf(o);
    }
}

// ---------------------------------------------------------------------------
// Layer-2 sparse attention + fused classifier + log_softmax. Block = 256.
__global__ __launch_bounds__(256) void att2_final_kernel(
    const bf16_t* __restrict__ Hbf, const float* __restrict__ f1,
    const float* __restrict__ f2, const int* __restrict__ deg,
    const int* __restrict__ cols, const float* __restrict__ linW,
    const float* __restrict__ linb, float* __restrict__ out) {
    int i = blockIdx.x;
    int t = threadIdx.x;
    __shared__ int jl[MAXDEG];
    __shared__ float sp[MAXDEG];
    __shared__ float red[4];
    __shared__ float part[3][FEAT];
    __shared__ float hrow[FEAT];
    __shared__ float clsred[16][NCLS];
    __shared__ float sl[NCLS];
    __shared__ int sdeg;
    if (t == 0) sdeg = deg[i];
    __syncthreads();
    int d = sdeg;
    int dpad = (d + 15) & ~15;        // multiple of 16 (4 waves x 4 unroll)
    if (t < dpad) jl[t] = (t < d) ? cols[i * MAXDEG + t] : i;
    __syncthreads();
    float e = 0.0f, lmax = -1e30f;
    if (t < d) {
        e = f1[i] + f2[jl[t]];
        e = e > 0.0f ? e : ALPHA * e;
        lmax = e;
    }
    for (int off = 32; off; off >>= 1) lmax = fmaxf(lmax, __shfl_down(lmax, off));
    if ((t & 63) == 0) red[t >> 6] = lmax;
    __syncthreads();
    float m = fmaxf(fmaxf(red[0], red[1]), fmaxf(red[2], red[3]));
    float p = 0.0f;
    if (t < d) p = __expf(e - m);
    if (t < dpad) sp[t] = p;          // pads write 0
    float ls = p;
    for (int off = 32; off; off >>= 1) ls += __shfl_down(ls, off);
    __syncthreads();                  // red[] reads done before overwrite
    if ((t & 63) == 0) red[t >> 6] = ls;
    __syncthreads();                  // publishes sp[] + red[]
    float s = red[0] + red[1] + red[2] + red[3];
    float inv = 1.0f / s;
    // whole-row gather, unroll 4
    const int slot = t >> 6;          // 0..3 (wave id)
    const int cg   = t & 63;          // col group (8 bf16)
    float acc[8] = {};
    for (int k0 = 0; k0 < dpad; k0 += 16) {
        float pw[4];
        const bf16_t* rp[4];
        #pragma unroll
        for (int j = 0; j < 4; ++j) {
            int k = k0 + j * 4 + slot;               // k < dpad guaranteed
            pw[j] = sp[k];
            rp[j] = Hbf + (size_t)jl[k] * FEAT + cg * 8;
        }
        #pragma unroll
        for (int j = 0; j < 4; ++j) {
            us8_t v = *(const us8_t*)rp[j];
            float pk = pw[j];
            #pragma unroll
            for (int q = 0; q < 8; ++q) acc[q] += pk * bfu2f(v[q]);
        }
    }
    // combine slots 1..3 into slot 0; slot 0 publishes h2 row to LDS
    if (slot > 0) {
        float* dst = &part[slot - 1][cg * 8];
        *(float4*)(dst)     = make_float4(acc[0], acc[1], acc[2], acc[3]);
        *(float4*)(dst + 4) = make_float4(acc[4], acc[5], acc[6], acc[7]);
    }
    __syncthreads();
    if (slot == 0) {
        #pragma unroll
        for (int sl2 = 0; sl2 < 3; ++sl2)
            #pragma unroll
            for (int j = 0; j < 8; ++j) acc[j] += part[sl2][cg * 8 + j];
        float* dst = &hrow[cg * 8];
        *(float4*)(dst)     = make_float4(acc[0] * inv, acc[1] * inv, acc[2] * inv, acc[3] * inv);
        *(float4*)(dst + 4) = make_float4(acc[4] * inv, acc[5] * inv, acc[6] * inv, acc[7] * inv);
    }
    __syncthreads();
    // classifier: class c = t&15, segment seg = t>>4 (32 features each)
    {
        int c = t & 15;
        int seg = t >> 4;
        float partial = 0.0f;
        int f0 = seg * 32;
        #pragma unroll 8
        for (int f = f0; f < f0 + 32; ++f) partial += hrow[f] * linW[f * NCLS + c];
        clsred[seg][c] = partial;
    }
    __syncthreads();
    if (t < NCLS) {
        float logit = linb[t];
        #pragma unroll
        for (int seg = 0; seg < 16; ++seg) logit += clsred[seg][t];
        logit = logit > 0.0f ? logit : __expf(logit) - 1.0f;   // ELU
        sl[t] = logit;
    }
    __syncthreads();
    if (t < NCLS) {
        float mm = sl[0];
        #pragma unroll
        for (int c = 1; c < NCLS; ++c) mm = fmaxf(mm, sl[c]);
        float ssum = 0.0f;
        #pragma unroll
        for (int c = 0; c < NCLS; ++c) ssum += __expf(sl[c] - mm);
        out[i * NCLS + t] = sl[t] - mm - logf(ssum);
    }
}

// ---------------------------------------------------------------------------
extern "C" void kernel_launch(void* const* d_in, const int* in_sizes, int n_in,
                              void* d_out, int out_size, void* d_ws, size_t ws_size,
                              hipStream_t stream) {
    const float* x        = (const float*)d_in[0];
    const float* rel      = (const float*)d_in[1];
    // d_in[2] rel_dict: unused (non-math constant per reference)
    const float* adj      = (const float*)d_in[3];
    const float* adj_ad   = (const float*)d_in[4];
    const float* W_heads  = (const float*)d_in[5];
    const float* a1_heads = (const float*)d_in[6];
    const float* a2_heads = (const float*)d_in[7];
    const float* W_out    = (const float*)d_in[8];
    const float* a1_out   = (const float*)d_in[9];
    const float* a2_out   = (const float*)d_in[10];
    const float* lin_W    = (const float*)d_in[11];
    const float* lin_b    = (const float*)d_in[12];
    float* out = (float*)d_out;

    char* ws = (char*)d_ws;
    bf16_t* Abf  = (bf16_t*)(ws);                                 // 4 MB  layer-1 GEMM input
    bf16_t* Abf2 = (bf16_t*)(ws + (4u  << 20));                   // 4 MB  layer-2 GEMM input
    bf16_t* Hbf1 = (bf16_t*)(ws + (8u  << 20));                   // 4 MB  layer-1 H (gather)
    bf16_t* Hbf2 = (bf16_t*)(ws + (12u << 20));                   // 4 MB  layer-2 H (gather)
    unsigned short* Rbf = (unsigned short*)(ws + (16u << 20));    // 4 MB  adj_ad@rel (bf16)
    bf16_t* WcT  = (bf16_t*)(ws + (20u << 20));                   // 0.5 MB
    bf16_t* WoT  = (bf16_t*)(ws + (20u << 20) + (512u << 10));    // 0.5 MB
    float*  f1   = (float*) (ws + (21u << 20));                   // 128 KB [8,4096]
    float*  f2   = (float*) (ws + (21u << 20) + (128u << 10));    // 128 KB
    float*  f1o  = (float*) (ws + (21u << 20) + (256u << 10));    // 16 KB
    float*  f2o  = (float*) (ws + (21u << 20) + (272u << 10));    // 16 KB
    int*    deg  = (int*)   (ws + (21u << 20) + (288u << 10));    // 16 KB
    int*    cols = (int*)   (ws + (22u << 20));                   // 2 MB  [4096,128]

    // fused front-end: CSR + (Rbf, Abf) + weight permutes + f-zero
    // (CSR co-runs with the harness fill drain — r10-best arrangement)
    prep_kernel<<<NN + 2048 + 2052, 256, 0, stream>>>(
        adj, deg, cols, adj_ad, rel, x, Rbf, Abf,
        W_heads, W_out, (unsigned short*)WcT, (unsigned short*)WoT, f1o, f2o);
    // layer-1 GEMM + fused f1/f2 dots (direct store)
    gemm_bf16_dot_kernel<<<dim3(64, 8), 256, 0, stream>>>(
        Abf, WcT, (unsigned short*)Hbf1, a1_heads, a2_heads, f1, f2, 0);
    // layer-1 attention + ELU + (+R, bf16) epilogue -> Abf2
    att1_kernel<<<NN, 512, 0, stream>>>(Hbf1, f1, f2, deg, cols, Rbf, Abf2);
    // layer-2 GEMM + fused f1o/f2o dots (atomicAdd across bn blocks)
    gemm_bf16_dot_kernel<<<dim3(64, 8), 256, 0, stream>>>(
        Abf2, WoT, (unsigned short*)Hbf2, a1_out, a2_out, f1o, f2o, 1);
    // layer-2 attention + classifier + log_softmax -> out (fused)
    att2_final_kernel<<<NN, 256, 0, stream>>>(Hbf2, f1o, f2o, deg, cols, lin_W, lin_b, out);
}